// Round 11
// baseline (269.104 us; speedup 1.0000x reference)
//
#include <hip/hip_runtime.h>
#include <stdint.h>

// ---------------------------------------------------------------------------
// SNN EMNIST forward: T=10, B=4096, IN=784, HID=256, NCLS=47
// splitk (EXACT 3-way bf16 W1) -> fused spikegen+MFMA gemm -> fused scan+out.
// R11 = R6 gemm body (builtin alignbit rotate, canonical kw=0..24 slab order
// — ORDER IS LOAD-BEARING: R10's rotated order flipped a near-threshold
// spike, absmax 1.9e-2) + s_sleep launch stagger: dispatch-wave 1/2 blocks
// sleep ~1.7/3.4us before the K-loop so co-resident blocks run hash (VALU)
// and MFMA phases out of phase instead of phase-locking (R6: 54% VALU duty).
// s_sleep changes no arithmetic -> output bitwise-identical to R6/R8.
// ---------------------------------------------------------------------------

#define T_STEPS 10
#define BATCH   4096
#define IN_DIM  784
#define HID     256
#define NCLS    47
#define NROWS   (T_STEPS * BATCH)        // 40960
#define KWORDS  25                       // ceil(784/32)
#define KPAD    800                      // 25*32

// d_ws layout (bytes):
//   [0, 41943040)          I_all  : float [40960][256]
//   [46039040, ...)        W1{hi,mid,lo}T : bf16 [256][800], 409600 B each
#define WS_IALL_OFF 0u
#define WS_W1HI_OFF 46039040u
#define WS_W1MD_OFF (46039040u + 409600u)
#define WS_W1LO_OFF (46039040u + 819200u)

typedef __attribute__((ext_vector_type(8))) short    bf16x8;
typedef __attribute__((ext_vector_type(4))) float    f32x4;
typedef __attribute__((ext_vector_type(4))) uint32_t u32x4;

// Rotate via alignbit intrinsic (best measured across 4 variants; both
// inline-asm forms regressed ~20 ops/hash via scheduling/allocator loss).
__device__ __forceinline__ uint32_t rotl32(uint32_t x, uint32_t r) {
    return __builtin_amdgcn_alignbit(x, x, 32u - r);
}

// JAX threefry2x32, key=(0,42), partitionable scheme: out = o0^o1, x0=0, x1=i.
__device__ __forceinline__ uint32_t tf_hash(uint32_t lo) {
    const uint32_t ks1 = 42u;
    const uint32_t ks2 = 0x1BD11BDAu ^ 42u;
    uint32_t x0 = 0u;
    uint32_t x1 = lo + ks1;
#define TF_RND(r) { x0 += x1; x1 = rotl32(x1, r); x1 ^= x0; }
    TF_RND(13) TF_RND(15) TF_RND(26) TF_RND(6)
    x0 += ks1; x1 += ks2 + 1u;
    TF_RND(17) TF_RND(29) TF_RND(16) TF_RND(24)
    x0 += ks2; x1 += 2u;                       // ks0 == 0
    TF_RND(13) TF_RND(15) TF_RND(26) TF_RND(6)
    x1 += ks1 + 3u;                            // x0 += ks0 is a no-op
    TF_RND(17) TF_RND(29) TF_RND(16) TF_RND(24)
    x0 += ks1; x1 += ks2 + 4u;
    TF_RND(13) TF_RND(15) TF_RND(26) TF_RND(6)
    x0 += ks2; x1 += 5u;                       // ks0 == 0
#undef TF_RND
    return x0 ^ x1;
}

// ---------------------------------------------------------------------------
// Kernel B0: split W1 (f32 [784][256]) into transposed bf16 hi/mid/lo
// [256][800]. EXACT: hi+mid+lo == w bitwise.
// ---------------------------------------------------------------------------
__global__ __launch_bounds__(256) void splitk_k(
        const float* __restrict__ W1, ushort* __restrict__ hiT,
        ushort* __restrict__ midT, ushort* __restrict__ loT) {
    int n = blockIdx.x;                  // 0..255
    for (int k = threadIdx.x; k < KPAD; k += 256) {
        float w = (k < IN_DIM) ? W1[k * HID + n] : 0.0f;
        uint32_t u = __float_as_uint(w);
        uint32_t hb = (u + 0x7FFFu + ((u >> 16) & 1u)) >> 16;    // RNE to bf16
        float hf = __uint_as_float(hb << 16);
        float r1 = w - hf;                                       // exact
        uint32_t u1 = __float_as_uint(r1);
        uint32_t mb = (u1 + 0x7FFFu + ((u1 >> 16) & 1u)) >> 16;  // RNE
        float mf2 = __uint_as_float(mb << 16);
        float r2 = r1 - mf2;                                     // exact
        uint32_t u2 = __float_as_uint(r2);
        uint32_t lb = (u2 + 0x7FFFu + ((u2 >> 16) & 1u)) >> 16;  // exact fit
        hiT [n * KPAD + k] = (ushort)hb;
        midT[n * KPAD + k] = (ushort)mb;
        loT [n * KPAD + k] = (ushort)lb;
    }
}

// ---------------------------------------------------------------------------
// Fused spikegen + GEMM: I_all = bernoulli(x) @ W1 + b1.
// Block: 64 rows (one t, 64 b) x 256 cols, 4 waves; wave = 64x64 = 4x4 tiles
// of 16x16x32. K-loop over 25 slabs in CANONICAL order. Per iter: [sync] ->
// issue B[kw] global_load_lds (3 planes) -> hash this slab's 8 spike
// bits/thread (VALU hides B L2 latency) -> ds_write A frag -> [sync] ->
// 48 MFMA. Sleep prologue staggers dispatch-waves by ~1/3, ~2/3 K-iter.
// XOR-swizzled 16B quarters keep every ds_read_b128 <=2-way (free).
// Accum order identical to R4/R6/R8 -> bitwise-identical I_all.
// ---------------------------------------------------------------------------
#define LDS_A  0
#define LDS_BH 4096
#define LDS_BM 20480
#define LDS_BL 36864

__global__ __launch_bounds__(256, 3) void fused_gemm_k(
        const ushort* __restrict__ hiT, const ushort* __restrict__ midT,
        const ushort* __restrict__ loT, const float* __restrict__ b1,
        const float* __restrict__ x, float* __restrict__ I_all) {
    __shared__ __align__(16) char lds[53248];

    const int tid = threadIdx.x;
    const int l   = tid & 63;
    const int wv  = tid >> 6;
    const int t   = blockIdx.x >> 6;     // 64 blocks per timestep
    const int b0  = (blockIdx.x & 63) << 6;
    const int m0  = blockIdx.x << 6;

    // De-phase co-resident blocks: dispatch-wave 1 sleeps ~4096 cyc (1.7us),
    // wave 2 ~8128 cyc (3.4us). Pure timing — no data effect.
    {
        const int ph = blockIdx.x >> 8;          // 0,1,2
        if (ph == 1)      __builtin_amdgcn_s_sleep(64);
        else if (ph == 2) __builtin_amdgcn_s_sleep(127);
    }

    f32x4 acc[4][4] = {};

    // fragment read addressing (shared swizzle sig for A and B)
    const int q   = l >> 4;
    const int sig = q ^ (l & 3) ^ ((l >> 2) & 3);
    const int a_base = LDS_A + ((l & 15) << 6) + (sig << 4);
    const int b_off  = (((wv << 6) + (l & 15)) << 6) + (sig << 4);

    // A-expansion thread mapping: row er (0..63), byte-group eq (0..3)
    const int er = tid >> 2;
    const int eq = tid & 3;
    const int ea = LDS_A + (er << 6) + ((eq ^ (er & 3) ^ ((er >> 2) & 3)) << 4);
    const int row_b = b0 + er;
    const float* xrow = x + (size_t)row_b * IN_DIM;
    const uint32_t ibase = (uint32_t)(row_b * IN_DIM)
                         + (uint32_t)t * (uint32_t)(BATCH * IN_DIM);

    for (int kw = 0; kw < KWORDS; ++kw) {
        __syncthreads();   // previous compute done with LDS

        // --- stage Bhi/Bmid/Blo K-slab (k in [kw*32,kw*32+32), 256 n) ---
#pragma unroll
        for (int i = 0; i < 4; ++i) {
            int s  = (wv << 8) + (i << 6) + l;          // slot 0..1023
            int n  = s >> 2;
            int qs = s & 3;
            int qd = qs ^ (n & 3) ^ ((n >> 2) & 3);     // swizzled data quarter
            size_t gb = (size_t)n * (KPAD * 2) + ((size_t)kw << 6) + ((size_t)qd << 4);
            int ldst = ((wv << 8) + (i << 6)) << 4;
            __builtin_amdgcn_global_load_lds(
                (const __attribute__((address_space(1))) void*)((const char*)hiT + gb),
                (__attribute__((address_space(3))) void*)(lds + LDS_BH + ldst),
                16, 0, 0);
            __builtin_amdgcn_global_load_lds(
                (const __attribute__((address_space(1))) void*)((const char*)midT + gb),
                (__attribute__((address_space(3))) void*)(lds + LDS_BM + ldst),
                16, 0, 0);
            __builtin_amdgcn_global_load_lds(
                (const __attribute__((address_space(1))) void*)((const char*)loT + gb),
                (__attribute__((address_space(3))) void*)(lds + LDS_BL + ldst),
                16, 0, 0);
        }

        // --- inline spikegen: hash 8 bits -> bf16 A fragment (16 B) ---
        {
            u32x4 v = {0u, 0u, 0u, 0u};
            // kw==24: k>=784 doesn't exist for eq>=2 -> keep zeros (also
            // guards the x OOB read on the last batch row).
            if (!(kw == 24 && eq >= 2)) {
                const int k0 = (kw << 5) + (eq << 3);
                float4 xa = *(const float4*)&xrow[k0];
                float4 xb = *(const float4*)&xrow[k0 + 4];
                const uint32_t ib = ibase + (uint32_t)k0;
                uint32_t c0 = ((float)(tf_hash(ib + 0u) >> 9) < xa.x * 8388608.0f) ? 0x3F80u : 0u;
                uint32_t c1 = ((float)(tf_hash(ib + 1u) >> 9) < xa.y * 8388608.0f) ? 0x3F800000u : 0u;
                uint32_t c2 = ((float)(tf_hash(ib + 2u) >> 9) < xa.z * 8388608.0f) ? 0x3F80u : 0u;
                uint32_t c3 = ((float)(tf_hash(ib + 3u) >> 9) < xa.w * 8388608.0f) ? 0x3F800000u : 0u;
                uint32_t c4 = ((float)(tf_hash(ib + 4u) >> 9) < xb.x * 8388608.0f) ? 0x3F80u : 0u;
                uint32_t c5 = ((float)(tf_hash(ib + 5u) >> 9) < xb.y * 8388608.0f) ? 0x3F800000u : 0u;
                uint32_t c6 = ((float)(tf_hash(ib + 6u) >> 9) < xb.z * 8388608.0f) ? 0x3F80u : 0u;
                uint32_t c7 = ((float)(tf_hash(ib + 7u) >> 9) < xb.w * 8388608.0f) ? 0x3F800000u : 0u;
                v.x = c0 | c1;  v.y = c2 | c3;  v.z = c4 | c5;  v.w = c6 | c7;
            }
            *(u32x4*)(lds + ea) = v;     // always store (zeros on tail)
        }

        __syncthreads();   // A visible + global_load_lds drained

        // --- compute: 4 mtiles x 4 ntiles x (hi,mid,lo) = 48 MFMA ---
        bf16x8 af[4];
#pragma unroll
        for (int mt = 0; mt < 4; ++mt)
            af[mt] = *(const bf16x8*)(lds + a_base + (mt << 10));
#pragma unroll
        for (int nt = 0; nt < 4; ++nt) {
            bf16x8 bh = *(const bf16x8*)(lds + LDS_BH + b_off + (nt << 10));
            bf16x8 bm = *(const bf16x8*)(lds + LDS_BM + b_off + (nt << 10));
            bf16x8 bl = *(const bf16x8*)(lds + LDS_BL + b_off + (nt << 10));
#pragma unroll
            for (int mt = 0; mt < 4; ++mt) {
                acc[mt][nt] = __builtin_amdgcn_mfma_f32_16x16x32_bf16(af[mt], bh, acc[mt][nt], 0, 0, 0);
                acc[mt][nt] = __builtin_amdgcn_mfma_f32_16x16x32_bf16(af[mt], bm, acc[mt][nt], 0, 0, 0);
                acc[mt][nt] = __builtin_amdgcn_mfma_f32_16x16x32_bf16(af[mt], bl, acc[mt][nt], 0, 0, 0);
            }
        }
    }

    // --- epilogue: acc -> I_all (+ b1) ---
    const int c0 = l & 15;
    float b1v[4];
#pragma unroll
    for (int nt = 0; nt < 4; ++nt)
        b1v[nt] = b1[(wv << 6) + (nt << 4) + c0];
#pragma unroll
    for (int mt = 0; mt < 4; ++mt) {
#pragma unroll
        for (int nt = 0; nt < 4; ++nt) {
            int col = (wv << 6) + (nt << 4) + c0;
#pragma unroll
            for (int r = 0; r < 4; ++r) {
                int row = m0 + (mt << 4) + (q << 2) + r;
                I_all[(size_t)row * HID + col] = acc[mt][nt][r] + b1v[nt];
            }
        }
    }
}

// ---------------------------------------------------------------------------
// Fused LIF scan + readout: per block, 16 batch rows.
// Phase 1: thread h scans 16 rows over t (exact reference op order) -> g in
// LDS. Phase 2: wave wv, lane c<47: out[b][c] = sum_h g[b][h]*Wr[h][c]
// (+ br*(1-2^-10)), h ascending.
// ---------------------------------------------------------------------------
__global__ __launch_bounds__(256) void scanout_k(
        const float* __restrict__ I_all, const float* __restrict__ Wr,
        const float* __restrict__ br, float* __restrict__ out) {
    __shared__ float gl[16 * 256];       // 16 KB
    const int tid = threadIdx.x;
    const int b0  = blockIdx.x << 4;

#pragma unroll 4
    for (int b = 0; b < 16; ++b) {
        const float* p = I_all + ((size_t)(b0 + b) << 8) + tid;
        float v = 0.f, ga = 0.f, wt = 0.0009765625f;   // 2^-10
#pragma unroll
        for (int t = 0; t < T_STEPS; ++t) {
            float I = p[(size_t)t * BATCH * HID];
            v = v + (I - v) * 0.5f;
            if (v >= 1.0f) { ga += wt; v = 0.f; }
            wt += wt;
        }
        gl[(b << 8) + tid] = ga;
    }
    __syncthreads();

    const int wv = tid >> 6;
    const int c  = tid & 63;
    if (c >= NCLS) return;
    float acc[4] = {0.f, 0.f, 0.f, 0.f};
    for (int h4 = 0; h4 < 64; ++h4) {
        float w0 = Wr[((h4 << 2) + 0) * NCLS + c];
        float w1 = Wr[((h4 << 2) + 1) * NCLS + c];
        float w2 = Wr[((h4 << 2) + 2) * NCLS + c];
        float w3 = Wr[((h4 << 2) + 3) * NCLS + c];
#pragma unroll
        for (int j = 0; j < 4; ++j) {
            float4 gg = *(float4*)&gl[(((wv << 2) + j) << 8) + (h4 << 2)];
            acc[j] = fmaf(gg.x, w0, acc[j]);
            acc[j] = fmaf(gg.y, w1, acc[j]);
            acc[j] = fmaf(gg.z, w2, acc[j]);
            acc[j] = fmaf(gg.w, w3, acc[j]);
        }
    }
    float brv = br[c] * 0.9990234375f;
#pragma unroll
    for (int j = 0; j < 4; ++j)
        out[(b0 + (wv << 2) + j) * NCLS + c] = acc[j] + brv;
}

extern "C" void kernel_launch(void* const* d_in, const int* in_sizes, int n_in,
                              void* d_out, int out_size, void* d_ws, size_t ws_size,
                              hipStream_t stream) {
    const float* x  = (const float*)d_in[0];
    const float* W1 = (const float*)d_in[1];
    const float* b1 = (const float*)d_in[2];
    const float* Wr = (const float*)d_in[3];
    const float* br = (const float*)d_in[4];
    float* out = (float*)d_out;

    float*  I_all = (float*) ((char*)d_ws + WS_IALL_OFF);
    ushort* w1hi  = (ushort*)((char*)d_ws + WS_W1HI_OFF);
    ushort* w1md  = (ushort*)((char*)d_ws + WS_W1MD_OFF);
    ushort* w1lo  = (ushort*)((char*)d_ws + WS_W1LO_OFF);

    splitk_k<<<HID, 256, 0, stream>>>(W1, w1hi, w1md, w1lo);
    fused_gemm_k<<<NROWS / 64, 256, 0, stream>>>(w1hi, w1md, w1lo, b1, x, I_all);
    scanout_k<<<BATCH / 16, 256, 0, stream>>>(I_all, Wr, br, out);
}

// Round 12
// 198.727 us; speedup vs baseline: 1.3541x; 1.3541x over previous
//
#include <hip/hip_runtime.h>
#include <stdint.h>

// ---------------------------------------------------------------------------
// SNN EMNIST forward: T=10, B=4096, IN=784, HID=256, NCLS=47
// splitk (EXACT 3-way bf16 W1) -> fused spikegen+MFMA gemm -> fused scan+out.
// R12 = R6 gemm body (canonical kw order, builtin alignbit rotate, NO sleep
// stagger — R11 falsified phase-lock theory) with all per-iter staging/hash
// ADDRESSES HOISTED: per-thread offsets are loop-invariant, pointers bump by
// a uniform +32 elements per K-slab. No data-path change -> bitwise-identical
// output to R6/R8 (absmax 4.882812e-4).
// ---------------------------------------------------------------------------

#define T_STEPS 10
#define BATCH   4096
#define IN_DIM  784
#define HID     256
#define NCLS    47
#define NROWS   (T_STEPS * BATCH)        // 40960
#define KWORDS  25                       // ceil(784/32)
#define KPAD    800                      // 25*32

// d_ws layout (bytes):
//   [0, 41943040)          I_all  : float [40960][256]
//   [46039040, ...)        W1{hi,mid,lo}T : bf16 [256][800], 409600 B each
#define WS_IALL_OFF 0u
#define WS_W1HI_OFF 46039040u
#define WS_W1MD_OFF (46039040u + 409600u)
#define WS_W1LO_OFF (46039040u + 819200u)

typedef __attribute__((ext_vector_type(8))) short    bf16x8;
typedef __attribute__((ext_vector_type(4))) float    f32x4;
typedef __attribute__((ext_vector_type(4))) uint32_t u32x4;

// Rotate via alignbit intrinsic (best measured across 4 variants; both
// inline-asm forms regressed via scheduling/allocator loss).
__device__ __forceinline__ uint32_t rotl32(uint32_t x, uint32_t r) {
    return __builtin_amdgcn_alignbit(x, x, 32u - r);
}

// JAX threefry2x32, key=(0,42), partitionable scheme: out = o0^o1, x0=0, x1=i.
__device__ __forceinline__ uint32_t tf_hash(uint32_t lo) {
    const uint32_t ks1 = 42u;
    const uint32_t ks2 = 0x1BD11BDAu ^ 42u;
    uint32_t x0 = 0u;
    uint32_t x1 = lo + ks1;
#define TF_RND(r) { x0 += x1; x1 = rotl32(x1, r); x1 ^= x0; }
    TF_RND(13) TF_RND(15) TF_RND(26) TF_RND(6)
    x0 += ks1; x1 += ks2 + 1u;
    TF_RND(17) TF_RND(29) TF_RND(16) TF_RND(24)
    x0 += ks2; x1 += 2u;                       // ks0 == 0
    TF_RND(13) TF_RND(15) TF_RND(26) TF_RND(6)
    x1 += ks1 + 3u;                            // x0 += ks0 is a no-op
    TF_RND(17) TF_RND(29) TF_RND(16) TF_RND(24)
    x0 += ks1; x1 += ks2 + 4u;
    TF_RND(13) TF_RND(15) TF_RND(26) TF_RND(6)
    x0 += ks2; x1 += 5u;                       // ks0 == 0
#undef TF_RND
    return x0 ^ x1;
}

// ---------------------------------------------------------------------------
// Kernel B0: split W1 (f32 [784][256]) into transposed bf16 hi/mid/lo
// [256][800]. EXACT: hi+mid+lo == w bitwise.
// ---------------------------------------------------------------------------
__global__ __launch_bounds__(256) void splitk_k(
        const float* __restrict__ W1, ushort* __restrict__ hiT,
        ushort* __restrict__ midT, ushort* __restrict__ loT) {
    int n = blockIdx.x;                  // 0..255
    for (int k = threadIdx.x; k < KPAD; k += 256) {
        float w = (k < IN_DIM) ? W1[k * HID + n] : 0.0f;
        uint32_t u = __float_as_uint(w);
        uint32_t hb = (u + 0x7FFFu + ((u >> 16) & 1u)) >> 16;    // RNE to bf16
        float hf = __uint_as_float(hb << 16);
        float r1 = w - hf;                                       // exact
        uint32_t u1 = __float_as_uint(r1);
        uint32_t mb = (u1 + 0x7FFFu + ((u1 >> 16) & 1u)) >> 16;  // RNE
        float mf2 = __uint_as_float(mb << 16);
        float r2 = r1 - mf2;                                     // exact
        uint32_t u2 = __float_as_uint(r2);
        uint32_t lb = (u2 + 0x7FFFu + ((u2 >> 16) & 1u)) >> 16;  // exact fit
        hiT [n * KPAD + k] = (ushort)hb;
        midT[n * KPAD + k] = (ushort)mb;
        loT [n * KPAD + k] = (ushort)lb;
    }
}

// ---------------------------------------------------------------------------
// Fused spikegen + GEMM: I_all = bernoulli(x) @ W1 + b1.
// Block: 64 rows (one t, 64 b) x 256 cols, 4 waves; wave = 64x64 = 4x4 tiles
// of 16x16x32. K-loop over 25 slabs in canonical order. Per iter: [sync] ->
// issue B[kw] global_load_lds (3 planes; per-thread source pointers hoisted,
// bumped +32 elem/iter) -> hash this slab's 8 spike bits/thread -> ds_write
// A frag -> [sync] -> 48 MFMA. XOR-swizzled 16B quarters keep every
// ds_read_b128 <=2-way (free). Accum order identical to R4/R6/R8.
// ---------------------------------------------------------------------------
#define LDS_A  0
#define LDS_BH 4096
#define LDS_BM 20480
#define LDS_BL 36864

__global__ __launch_bounds__(256, 3) void fused_gemm_k(
        const ushort* __restrict__ hiT, const ushort* __restrict__ midT,
        const ushort* __restrict__ loT, const float* __restrict__ b1,
        const float* __restrict__ x, float* __restrict__ I_all) {
    __shared__ __align__(16) char lds[53248];

    const int tid = threadIdx.x;
    const int l   = tid & 63;
    const int wv  = tid >> 6;
    const int t   = blockIdx.x >> 6;     // 64 blocks per timestep
    const int b0  = (blockIdx.x & 63) << 6;
    const int m0  = blockIdx.x << 6;

    f32x4 acc[4][4] = {};

    // fragment read addressing (shared swizzle sig for A and B)
    const int q   = l >> 4;
    const int sig = q ^ (l & 3) ^ ((l >> 2) & 3);
    const int a_base = LDS_A + ((l & 15) << 6) + (sig << 4);
    const int b_off  = (((wv << 6) + (l & 15)) << 6) + (sig << 4);

    // ---- loop-invariant staging addresses (hoisted out of the K-loop) ----
    // slot s = wv*256 + i*64 + l; n = s>>2; qd = (s&3)^(n&3)^((n>>2)&3).
    // Source element offset = n*KPAD + qd*8 (invariant) + kw*32 (uniform bump).
    const ushort* hi_p[4];
    const ushort* md_p[4];
    const ushort* lo_p[4];
    int ldst_c[4];
#pragma unroll
    for (int i = 0; i < 4; ++i) {
        int s  = (wv << 8) + (i << 6) + l;
        int n  = s >> 2;
        int qs = s & 3;
        int qd = qs ^ (n & 3) ^ ((n >> 2) & 3);
        size_t eoff = (size_t)n * KPAD + ((size_t)qd << 3);
        hi_p[i] = hiT  + eoff;
        md_p[i] = midT + eoff;
        lo_p[i] = loT  + eoff;
        ldst_c[i] = ((wv << 8) + (i << 6)) << 4;
    }

    // A-expansion thread mapping: row er (0..63), byte-group eq (0..3)
    const int er = tid >> 2;
    const int eq = tid & 3;
    const int ea = LDS_A + (er << 6) + ((eq ^ (er & 3) ^ ((er >> 2) & 3)) << 4);
    const int row_b = b0 + er;
    const float* xp = x + (size_t)row_b * IN_DIM + (eq << 3);   // bumped +32/iter
    uint32_t ib = (uint32_t)(row_b * IN_DIM) + (uint32_t)(eq << 3)
                + (uint32_t)t * (uint32_t)(BATCH * IN_DIM);     // bumped +32/iter

    for (int kw = 0; kw < KWORDS; ++kw) {
        __syncthreads();   // previous compute done with LDS

        // --- stage Bhi/Bmid/Blo K-slab (hoisted pointers) ---
#pragma unroll
        for (int i = 0; i < 4; ++i) {
            __builtin_amdgcn_global_load_lds(
                (const __attribute__((address_space(1))) void*)hi_p[i],
                (__attribute__((address_space(3))) void*)(lds + LDS_BH + ldst_c[i]),
                16, 0, 0);
            __builtin_amdgcn_global_load_lds(
                (const __attribute__((address_space(1))) void*)md_p[i],
                (__attribute__((address_space(3))) void*)(lds + LDS_BM + ldst_c[i]),
                16, 0, 0);
            __builtin_amdgcn_global_load_lds(
                (const __attribute__((address_space(1))) void*)lo_p[i],
                (__attribute__((address_space(3))) void*)(lds + LDS_BL + ldst_c[i]),
                16, 0, 0);
            hi_p[i] += 32;  md_p[i] += 32;  lo_p[i] += 32;
        }

        // --- inline spikegen: hash 8 bits -> bf16 A fragment (16 B) ---
        {
            u32x4 v = {0u, 0u, 0u, 0u};
            // kw==24: k>=784 doesn't exist for eq>=2 -> keep zeros (also
            // guards the x OOB read on the last batch row).
            if (!(kw == 24 && eq >= 2)) {
                float4 xa = *(const float4*)xp;
                float4 xb = *(const float4*)(xp + 4);
                uint32_t c0 = ((float)(tf_hash(ib + 0u) >> 9) < xa.x * 8388608.0f) ? 0x3F80u : 0u;
                uint32_t c1 = ((float)(tf_hash(ib + 1u) >> 9) < xa.y * 8388608.0f) ? 0x3F800000u : 0u;
                uint32_t c2 = ((float)(tf_hash(ib + 2u) >> 9) < xa.z * 8388608.0f) ? 0x3F80u : 0u;
                uint32_t c3 = ((float)(tf_hash(ib + 3u) >> 9) < xa.w * 8388608.0f) ? 0x3F800000u : 0u;
                uint32_t c4 = ((float)(tf_hash(ib + 4u) >> 9) < xb.x * 8388608.0f) ? 0x3F80u : 0u;
                uint32_t c5 = ((float)(tf_hash(ib + 5u) >> 9) < xb.y * 8388608.0f) ? 0x3F800000u : 0u;
                uint32_t c6 = ((float)(tf_hash(ib + 6u) >> 9) < xb.z * 8388608.0f) ? 0x3F80u : 0u;
                uint32_t c7 = ((float)(tf_hash(ib + 7u) >> 9) < xb.w * 8388608.0f) ? 0x3F800000u : 0u;
                v.x = c0 | c1;  v.y = c2 | c3;  v.z = c4 | c5;  v.w = c6 | c7;
            }
            *(u32x4*)(lds + ea) = v;     // always store (zeros on tail)
        }
        xp += 32;  ib += 32u;

        __syncthreads();   // A visible + global_load_lds drained

        // --- compute: 4 mtiles x 4 ntiles x (hi,mid,lo) = 48 MFMA ---
        bf16x8 af[4];
#pragma unroll
        for (int mt = 0; mt < 4; ++mt)
            af[mt] = *(const bf16x8*)(lds + a_base + (mt << 10));
#pragma unroll
        for (int nt = 0; nt < 4; ++nt) {
            bf16x8 bh = *(const bf16x8*)(lds + LDS_BH + b_off + (nt << 10));
            bf16x8 bm = *(const bf16x8*)(lds + LDS_BM + b_off + (nt << 10));
            bf16x8 bl = *(const bf16x8*)(lds + LDS_BL + b_off + (nt << 10));
#pragma unroll
            for (int mt = 0; mt < 4; ++mt) {
                acc[mt][nt] = __builtin_amdgcn_mfma_f32_16x16x32_bf16(af[mt], bh, acc[mt][nt], 0, 0, 0);
                acc[mt][nt] = __builtin_amdgcn_mfma_f32_16x16x32_bf16(af[mt], bm, acc[mt][nt], 0, 0, 0);
                acc[mt][nt] = __builtin_amdgcn_mfma_f32_16x16x32_bf16(af[mt], bl, acc[mt][nt], 0, 0, 0);
            }
        }
    }

    // --- epilogue: acc -> I_all (+ b1) ---
    const int c0 = l & 15;
    float b1v[4];
#pragma unroll
    for (int nt = 0; nt < 4; ++nt)
        b1v[nt] = b1[(wv << 6) + (nt << 4) + c0];
#pragma unroll
    for (int mt = 0; mt < 4; ++mt) {
#pragma unroll
        for (int nt = 0; nt < 4; ++nt) {
            int col = (wv << 6) + (nt << 4) + c0;
#pragma unroll
            for (int r = 0; r < 4; ++r) {
                int row = m0 + (mt << 4) + (q << 2) + r;
                I_all[(size_t)row * HID + col] = acc[mt][nt][r] + b1v[nt];
            }
        }
    }
}

// ---------------------------------------------------------------------------
// Fused LIF scan + readout: per block, 16 batch rows.
// Phase 1: thread h scans 16 rows over t (exact reference op order) -> g in
// LDS. Phase 2: wave wv, lane c<47: out[b][c] = sum_h g[b][h]*Wr[h][c]
// (+ br*(1-2^-10)), h ascending.
// ---------------------------------------------------------------------------
__global__ __launch_bounds__(256) void scanout_k(
        const float* __restrict__ I_all, const float* __restrict__ Wr,
        const float* __restrict__ br, float* __restrict__ out) {
    __shared__ float gl[16 * 256];       // 16 KB
    const int tid = threadIdx.x;
    const int b0  = blockIdx.x << 4;

#pragma unroll 4
    for (int b = 0; b < 16; ++b) {
        const float* p = I_all + ((size_t)(b0 + b) << 8) + tid;
        float v = 0.f, ga = 0.f, wt = 0.0009765625f;   // 2^-10
#pragma unroll
        for (int t = 0; t < T_STEPS; ++t) {
            float I = p[(size_t)t * BATCH * HID];
            v = v + (I - v) * 0.5f;
            if (v >= 1.0f) { ga += wt; v = 0.f; }
            wt += wt;
        }
        gl[(b << 8) + tid] = ga;
    }
    __syncthreads();

    const int wv = tid >> 6;
    const int c  = tid & 63;
    if (c >= NCLS) return;
    float acc[4] = {0.f, 0.f, 0.f, 0.f};
    for (int h4 = 0; h4 < 64; ++h4) {
        float w0 = Wr[((h4 << 2) + 0) * NCLS + c];
        float w1 = Wr[((h4 << 2) + 1) * NCLS + c];
        float w2 = Wr[((h4 << 2) + 2) * NCLS + c];
        float w3 = Wr[((h4 << 2) + 3) * NCLS + c];
#pragma unroll
        for (int j = 0; j < 4; ++j) {
            float4 gg = *(float4*)&gl[(((wv << 2) + j) << 8) + (h4 << 2)];
            acc[j] = fmaf(gg.x, w0, acc[j]);
            acc[j] = fmaf(gg.y, w1, acc[j]);
            acc[j] = fmaf(gg.z, w2, acc[j]);
            acc[j] = fmaf(gg.w, w3, acc[j]);
        }
    }
    float brv = br[c] * 0.9990234375f;
#pragma unroll
    for (int j = 0; j < 4; ++j)
        out[(b0 + (wv << 2) + j) * NCLS + c] = acc[j] + brv;
}

extern "C" void kernel_launch(void* const* d_in, const int* in_sizes, int n_in,
                              void* d_out, int out_size, void* d_ws, size_t ws_size,
                              hipStream_t stream) {
    const float* x  = (const float*)d_in[0];
    const float* W1 = (const float*)d_in[1];
    const float* b1 = (const float*)d_in[2];
    const float* Wr = (const float*)d_in[3];
    const float* br = (const float*)d_in[4];
    float* out = (float*)d_out;

    float*  I_all = (float*) ((char*)d_ws + WS_IALL_OFF);
    ushort* w1hi  = (ushort*)((char*)d_ws + WS_W1HI_OFF);
    ushort* w1md  = (ushort*)((char*)d_ws + WS_W1MD_OFF);
    ushort* w1lo  = (ushort*)((char*)d_ws + WS_W1LO_OFF);

    splitk_k<<<HID, 256, 0, stream>>>(W1, w1hi, w1md, w1lo);
    fused_gemm_k<<<NROWS / 64, 256, 0, stream>>>(w1hi, w1md, w1lo, b1, x, I_all);
    scanout_k<<<BATCH / 16, 256, 0, stream>>>(I_all, Wr, br, out);
}